// Round 12
// baseline (203.595 us; speedup 1.0000x reference)
//
#include <hip/hip_runtime.h>
#include <math.h>

#define N_NODES 100000
#define N_EDGES 3200000
#define D_FEAT 128
#define H1 32
#define H2 16
#define NC 8

#define NB2 782            // buckets of 128 dst nodes: ceil(100000/128)
#define BCAP2 6144         // ebuf slots per 128-bucket (mean 4093)
#define HCAP 6144          // srt slots per fuse1 block
#define EPB 4096           // edges per scatter block
#define EPT 8              // edges per thread (EPB / 512)
#define NSB ((N_EDGES + EPB - 1) / EPB)   // 782 scatter blocks

#define P_NODES 32         // nodes per pull2 block
#define P_CAP 3072         // staged col_idx slots in pull2

typedef short s16x8 __attribute__((ext_vector_type(8)));
typedef float f32x4 __attribute__((ext_vector_type(4)));

__device__ inline unsigned short f2bf(float f) {
    unsigned int u = __float_as_uint(f);
    u += 0x7FFF + ((u >> 16) & 1);
    return (unsigned short)(u >> 16);
}
__device__ inline float bf2f(unsigned short h) {
    return __uint_as_float((unsigned int)h << 16);
}

// 64-lane inclusive scan, no barriers
__device__ inline int wave_scan_incl(int v, int lane) {
#pragma unroll
    for (int off = 1; off < 64; off <<= 1) {
        const int t = __shfl_up(v, off, 64);
        if (lane >= off) v += t;
    }
    return v;
}

// 16 fp8 accumulate from one uint4 (16B); selector must be a literal
__device__ inline void acc16(float* a, uint4 q) {
#pragma unroll
    for (int d = 0; d < 4; ++d) {
        const unsigned int w = (&q.x)[d];
        a[d * 4 + 0] += __builtin_amdgcn_cvt_f32_fp8(w, 0);
        a[d * 4 + 1] += __builtin_amdgcn_cvt_f32_fp8(w, 1);
        a[d * 4 + 2] += __builtin_amdgcn_cvt_f32_fp8(w, 2);
        a[d * 4 + 3] += __builtin_amdgcn_cvt_f32_fp8(w, 3);
    }
}

// 8 bf16 accumulate from one uint4 (16B)
__device__ inline void acc8b(float* a, uint4 q) {
#pragma unroll
    for (int d = 0; d < 4; ++d) {
        const unsigned int w = (&q.x)[d];
        a[d * 2]     += bf2f((unsigned short)w);
        a[d * 2 + 1] += bf2f((unsigned short)(w >> 16));
    }
}

// ---------------- k_pre: scatter blocks [0,NSB) + gemm blocks [NSB,NSB+391) --

__global__ __launch_bounds__(512) void k_pre(const int* __restrict__ ei,
                                             const float* __restrict__ x,
                                             const float* __restrict__ W1,
                                             int* __restrict__ bucket_cursor,
                                             int* __restrict__ ebuf,
                                             unsigned short* __restrict__ y16) {
    __shared__ union {
        struct {
            int hist[NB2], lofs[NB2], rank[NB2], gb[NB2];   // 12.5 KB
            int wsumA[8], wsumB[8], tot, is64;
            int pay[EPB];                // 16 KB
            unsigned short pbk[EPB];     // 8 KB
        } sc;                            // ~37 KB
        struct {
            unsigned short wf[2 * 4 * 64 * 8];  // 8 KB W1 fragments
            float os[8][16][33];                // 16.9 KB
        } gm;                            // ~25 KB
    } u;
    const int tid = threadIdx.x;
    const int lane = tid & 63;
    const int wid = tid >> 6;

    if (blockIdx.x >= NSB) {
        // ---------------- gemm path ----------------
        const int gb_ = blockIdx.x - NSB;
        for (int idx = tid; idx < 2 * 4 * 64 * 8; idx += 512) {
            const int j  = idx & 7;
            const int ln = (idx >> 3) & 63;
            const int kk = (idx >> 9) & 3;
            const int nt = idx >> 11;
            const int k = kk * 32 + ((ln >> 4) << 3) + j;
            const int n = nt * 16 + (ln & 15);
            u.gm.wf[idx] = f2bf(W1[k * H1 + n]);
        }
        __syncthreads();
        const int w = tid >> 6;
        const int m = lane & 15;
        const int quad = lane >> 4;
        const int rl = lane >> 2;
        const int seg = lane & 3;
        const s16x8* bf = (const s16x8*)u.gm.wf;
#pragma unroll
        for (int t = 0; t < 2; ++t) {
            const int row0 = (gb_ << 8) + (w * 2 + t) * 16;
            const bool act = (row0 < N_NODES);   // 160 % 16 == 0: full tiles
            if (act) {
                f32x4 acc0 = {0.f, 0.f, 0.f, 0.f};
                f32x4 acc1 = {0.f, 0.f, 0.f, 0.f};
#pragma unroll
                for (int kk = 0; kk < 4; ++kk) {
                    const float* xp = x + (size_t)(row0 + m) * D_FEAT + kk * 32 + quad * 8;
                    const float4 p0 = ((const float4*)xp)[0];
                    const float4 p1 = ((const float4*)xp)[1];
                    s16x8 a;
                    a[0] = (short)f2bf(p0.x); a[1] = (short)f2bf(p0.y);
                    a[2] = (short)f2bf(p0.z); a[3] = (short)f2bf(p0.w);
                    a[4] = (short)f2bf(p1.x); a[5] = (short)f2bf(p1.y);
                    a[6] = (short)f2bf(p1.z); a[7] = (short)f2bf(p1.w);
                    acc0 = __builtin_amdgcn_mfma_f32_16x16x32_bf16(a, bf[kk * 64 + lane], acc0, 0, 0, 0);
                    acc1 = __builtin_amdgcn_mfma_f32_16x16x32_bf16(a, bf[(4 + kk) * 64 + lane], acc1, 0, 0, 0);
                }
#pragma unroll
                for (int r = 0; r < 4; ++r) {
                    u.gm.os[w][quad * 4 + r][m]      = acc0[r];
                    u.gm.os[w][quad * 4 + r][16 + m] = acc1[r];
                }
            }
            __syncthreads();
            if (act) {
                const int row = row0 + rl;
                const float* p = &u.gm.os[w][rl][seg * 8];
                uint4 o;
                o.x = (unsigned int)f2bf(p[0]) | ((unsigned int)f2bf(p[1]) << 16);
                o.y = (unsigned int)f2bf(p[2]) | ((unsigned int)f2bf(p[3]) << 16);
                o.z = (unsigned int)f2bf(p[4]) | ((unsigned int)f2bf(p[5]) << 16);
                o.w = (unsigned int)f2bf(p[6]) | ((unsigned int)f2bf(p[7]) << 16);
                *(uint4*)(y16 + (size_t)row * 32 + seg * 8) = o;
            }
            __syncthreads();
        }
        return;
    }

    // ---------------- scatter path (128-dst buckets) ----------------
    for (int i = tid; i < NB2; i += 512) { u.sc.hist[i] = 0; u.sc.rank[i] = 0; }
    if (tid < 64) {                          // wave-local is64 detect
        int v = ei[2 * tid + 1];
#pragma unroll
        for (int off = 1; off < 64; off <<= 1) v |= __shfl_xor(v, off, 64);
        if (tid == 0) u.sc.is64 = (v == 0) ? 1 : 0;
    }
    __syncthreads();
    const int e0 = blockIdx.x * EPB;
    const int n = min(EPB, N_EDGES - e0);    // always even
    const bool is64 = (u.sc.is64 != 0);
    int rs[EPT], rd[EPT];
    if (is64) {
#pragma unroll
        for (int k = 0; k < EPT / 2; ++k) {
            const int i = 2 * (tid + k * 512);
            if (i < n) {
                const int e = e0 + i;
                const int4 s = *(const int4*)&ei[2 * e];
                const int4 d = *(const int4*)&ei[2 * N_EDGES + 2 * e];
                rs[2 * k] = s.x; rs[2 * k + 1] = s.z;
                rd[2 * k] = d.x; rd[2 * k + 1] = d.z;
                atomicAdd(&u.sc.hist[d.x >> 7], 1);
                atomicAdd(&u.sc.hist[d.z >> 7], 1);
            }
        }
    } else {
#pragma unroll
        for (int k = 0; k < EPT / 2; ++k) {
            const int i = 2 * (tid + k * 512);
            if (i < n) {
                const int e = e0 + i;
                const int2 s = *(const int2*)&ei[e];
                const int2 d = *(const int2*)&ei[N_EDGES + e];
                rs[2 * k] = s.x; rs[2 * k + 1] = s.y;
                rd[2 * k] = d.x; rd[2 * k + 1] = d.y;
                atomicAdd(&u.sc.hist[d.x >> 7], 1);
                atomicAdd(&u.sc.hist[d.y >> 7], 1);
            }
        }
    }
    __syncthreads();
    // two-chunk 782-wide scan: chunk 1 [0,512)
    const int own0 = u.sc.hist[tid];
    int incl0 = wave_scan_incl(own0, lane);
    if (lane == 63) u.sc.wsumA[wid] = incl0;
    __syncthreads();
    if (tid == 0) {
        int r = 0;
#pragma unroll
        for (int w = 0; w < 8; ++w) { const int t = u.sc.wsumA[w]; u.sc.wsumA[w] = r; r += t; }
        u.sc.tot = r;
    }
    __syncthreads();
    incl0 += u.sc.wsumA[wid];
    u.sc.lofs[tid] = incl0 - own0;
    // chunk 2 [512, 782)
    const int own1 = (tid < NB2 - 512) ? u.sc.hist[512 + tid] : 0;
    int incl1 = wave_scan_incl(own1, lane);
    if (lane == 63) u.sc.wsumB[wid] = incl1;
    __syncthreads();
    if (tid == 0) {
        int r = 0;
#pragma unroll
        for (int w = 0; w < 8; ++w) { const int t = u.sc.wsumB[w]; u.sc.wsumB[w] = r; r += t; }
    }
    __syncthreads();
    incl1 += u.sc.wsumB[wid] + u.sc.tot;
    if (tid < NB2 - 512) u.sc.lofs[512 + tid] = incl1 - own1;
    // global cursor reservation per bucket
    for (int i = tid; i < NB2; i += 512) {
        const int ownI = u.sc.hist[i];
        if (ownI > 0) u.sc.gb[i] = i * BCAP2 + atomicAdd(&bucket_cursor[i], ownI);
    }
    __syncthreads();
#pragma unroll
    for (int k = 0; k < EPT / 2; ++k) {
        const int i = 2 * (tid + k * 512);
        if (i < n) {
#pragma unroll
            for (int j = 0; j < 2; ++j) {
                const int b = rd[2 * k + j] >> 7;
                const int p = u.sc.lofs[b] + atomicAdd(&u.sc.rank[b], 1);
                u.sc.pay[p] = (rs[2 * k + j] << 8) | (rd[2 * k + j] & 255);
                u.sc.pbk[p] = (unsigned short)b;
            }
        }
    }
    __syncthreads();
    for (int p = tid; p < n; p += 512) {
        const int b = u.sc.pbk[p];
        ebuf[u.sc.gb[b] + (p - u.sc.lofs[b])] = u.sc.pay[p];
    }
}

// ---------------- k_mid: degree + dinv-scale + fp8 pack + bbase scan ---------

__global__ __launch_bounds__(512) void k_mid(const int* __restrict__ ebuf,
                                             const int* __restrict__ bucket_cursor,
                                             const unsigned short* __restrict__ y16,
                                             int* __restrict__ degc,
                                             float* __restrict__ dinv,
                                             int* __restrict__ bbase,
                                             unsigned int* __restrict__ u1q) {
    __shared__ int cnt[256];
    __shared__ int wsA[8], wsB[8];
    __shared__ int tt;
    const int b = blockIdx.x;
    const int tid = threadIdx.x;
    if (tid < 256) cnt[tid] = 0;
    __syncthreads();
#pragma unroll
    for (int j = 0; j < 2; ++j) {
        const int b2 = 2 * b + j;
        const int nbj = bucket_cursor[b2];
        const int rbj = b2 * BCAP2;
        for (int i = tid; i < nbj; i += 512)
            atomicAdd(&cnt[ebuf[rbj + i] & 255], 1);   // bit7 = bucket parity
    }
    __syncthreads();
    if (tid < 256) {
        const int v = (b << 8) + tid;
        const int cn = cnt[tid];
        degc[v] = cn;
        if (v < N_NODES) {
            const float dv = rsqrtf(1.0f + (float)cn);
            dinv[v] = dv;
            unsigned int r[16];
            const uint4* yp = (const uint4*)(y16 + (size_t)v * 32);
            *(uint4*)&r[0]  = yp[0];
            *(uint4*)&r[4]  = yp[1];
            *(uint4*)&r[8]  = yp[2];
            *(uint4*)&r[12] = yp[3];
            unsigned int wq[8];
#pragma unroll
            for (int j = 0; j < 8; ++j) {
                const float c0 = bf2f((unsigned short)r[2 * j]) * dv;
                const float c1 = bf2f((unsigned short)(r[2 * j] >> 16)) * dv;
                const float c2 = bf2f((unsigned short)r[2 * j + 1]) * dv;
                const float c3 = bf2f((unsigned short)(r[2 * j + 1] >> 16)) * dv;
                unsigned int pk = __builtin_amdgcn_cvt_pk_fp8_f32(c0, c1, 0u, false);
                wq[j] = __builtin_amdgcn_cvt_pk_fp8_f32(c2, c3, pk, true);
            }
            uint4 oa; oa.x = wq[0]; oa.y = wq[1]; oa.z = wq[2]; oa.w = wq[3];
            uint4 ob; ob.x = wq[4]; ob.y = wq[5]; ob.z = wq[6]; ob.w = wq[7];
            ((uint4*)u1q)[(size_t)v * 2]     = oa;
            ((uint4*)u1q)[(size_t)v * 2 + 1] = ob;
        }
    }
    if (b == 0) {                        // bbase: exclusive scan of 782 counts
        const int lane = tid & 63, wid = tid >> 6;
        const int o0 = bucket_cursor[tid];
        int i0 = wave_scan_incl(o0, lane);
        if (lane == 63) wsA[wid] = i0;
        __syncthreads();
        if (tid == 0) {
            int r = 0;
#pragma unroll
            for (int w = 0; w < 8; ++w) { const int t = wsA[w]; wsA[w] = r; r += t; }
            tt = r;
        }
        __syncthreads();
        i0 += wsA[wid];
        bbase[tid] = i0 - o0;
        const int o1 = (tid < NB2 - 512) ? bucket_cursor[512 + tid] : 0;
        int i1 = wave_scan_incl(o1, lane);
        if (lane == 63) wsB[wid] = i1;
        __syncthreads();
        if (tid == 0) {
            int r = 0;
#pragma unroll
            for (int w = 0; w < 8; ++w) { const int t = wsB[w]; wsB[w] = r; r += t; }
        }
        __syncthreads();
        i1 += wsB[wid] + tt;
        if (tid < NB2 - 512) bbase[512 + tid] = i1 - o1;
    }
}

// ---------------- fused sort + pull1 + GEMM2 (16B gather, 2 streams) ---------

__global__ __launch_bounds__(512) void k_fuse1(const int* __restrict__ ebuf,
                                               const int* __restrict__ bucket_cursor,
                                               const int* __restrict__ degc,
                                               const int* __restrict__ bbase,
                                               const unsigned int* __restrict__ u1q,
                                               const float* __restrict__ b1,
                                               const float* __restrict__ W2,
                                               int* __restrict__ row_ptr,
                                               int* __restrict__ col_idx,
                                               unsigned int* __restrict__ u2b) {
    __shared__ int srt[HCAP];       // 24 KB sorted src of own bucket
    __shared__ int cnt[128];
    __shared__ int cur[128];
    __shared__ int wsum2[2];
    __shared__ float Ws[H1 * H2];   // 2 KB
    __shared__ float hs[128][33];   // 16.9 KB
    const int b2 = blockIdx.x;
    const int tid = threadIdx.x;
    const int lane = tid & 63;
    const int wid = tid >> 6;
    if (tid < 128) cnt[tid] = degc[(b2 << 7) + tid];
    for (int i = tid; i < H1 * H2; i += 512) Ws[i] = W2[i];
    const int wb = bbase[b2];
    const int nb = bucket_cursor[b2];
    const int rb = b2 * BCAP2;
    __syncthreads();
    // 128-wide scan of cnt (waves 0,1)
    int ownc = 0, inclc = 0;
    if (tid < 128) {
        ownc = cnt[tid];
        inclc = wave_scan_incl(ownc, lane);
        if (lane == 63) wsum2[wid] = inclc;
    }
    __syncthreads();
    if (tid < 128) {
        if (wid == 1) inclc += wsum2[0];
        const int excl = inclc - ownc;
        cur[tid] = excl;
        const int v = (b2 << 7) + tid;
        if (v <= N_NODES) row_ptr[v] = wb + excl;   // covers row_ptr[N_NODES]
    }
    __syncthreads();
    // scatter own bucket's edges into srt (local slots), sorted by dst
    for (int i = tid; i < nb; i += 512) {
        const int pk = ebuf[rb + i];
        const int slot = atomicAdd(&cur[pk & 127], 1);
        srt[slot] = pk >> 8;
    }
    __syncthreads();
    // coalesced col_idx write for pull2
    for (int i = tid; i < nb; i += 512)
        col_idx[wb + i] = srt[i];
    // per-node register gather: 2 streams x 2 subs, uint4 loads, depth 4
    const int nn = tid >> 2;        // node-in-bucket 0..127
    const int st = (tid >> 1) & 1;  // edge stream (even/odd)
    const int sub = tid & 1;        // feature half (16B)
    const int v = (b2 << 7) + nn;
    float a[16];
#pragma unroll
    for (int k = 0; k < 16; ++k) a[k] = 0.0f;
    int cn = 0;
    if (v < N_NODES) {
        const uint4* b16 = (const uint4*)u1q;
        if (st == 0) acc16(a, b16[(size_t)v * 2 + sub]);   // self-loop once
        cn = cnt[nn];
        const int e = cur[nn];                             // local inclusive end
        int j = e - cn + st;
        for (; j + 6 < e; j += 8) {                        // 4 edges/stream iter
            const int s0 = srt[j];
            const int s1 = srt[j + 2];
            const int s2 = srt[j + 4];
            const int s3 = srt[j + 6];
            const uint4 q0 = b16[(size_t)s0 * 2 + sub];
            const uint4 q1 = b16[(size_t)s1 * 2 + sub];
            const uint4 q2 = b16[(size_t)s2 * 2 + sub];
            const uint4 q3 = b16[(size_t)s3 * 2 + sub];
            acc16(a, q0); acc16(a, q1); acc16(a, q2); acc16(a, q3);
        }
        for (; j < e; j += 2) {
            acc16(a, b16[(size_t)srt[j] * 2 + sub]);
        }
    }
    // combine even/odd streams
#pragma unroll
    for (int k = 0; k < 16; ++k) a[k] += __shfl_xor(a[k], 2, 64);
    if (v < N_NODES && st == 0) {
        const float dv = rsqrtf(1.0f + (float)cn);
        float bb[16];
        *(float4*)&bb[0]  = ((const float4*)b1)[sub * 4 + 0];
        *(float4*)&bb[4]  = ((const float4*)b1)[sub * 4 + 1];
        *(float4*)&bb[8]  = ((const float4*)b1)[sub * 4 + 2];
        *(float4*)&bb[12] = ((const float4*)b1)[sub * 4 + 3];
        float* hp = &hs[nn][sub * 16];
#pragma unroll
        for (int k = 0; k < 16; ++k)
            hp[k] = fmaxf(fmaf(a[k], dv, bb[k]), 0.0f);
        if (sub == 0) hs[nn][32] = dv;
    }
    __syncthreads();
    {
        const int nn2 = tid >> 2;
        const int jq = tid & 3;
        const int v2 = (b2 << 7) + nn2;
        if (v2 < N_NODES) {
            const int j0 = jq * 4;
            const float dv = hs[nn2][32];
            float s0 = 0.f, s1 = 0.f, s2 = 0.f, s3 = 0.f;
#pragma unroll
            for (int k = 0; k < H1; ++k) {
                const float hk = hs[nn2][k];
                s0 = fmaf(hk, Ws[k * H2 + j0 + 0], s0);
                s1 = fmaf(hk, Ws[k * H2 + j0 + 1], s1);
                s2 = fmaf(hk, Ws[k * H2 + j0 + 2], s2);
                s3 = fmaf(hk, Ws[k * H2 + j0 + 3], s3);
            }
            uint2 o;
            o.x = (unsigned int)f2bf(s0 * dv) | ((unsigned int)f2bf(s1 * dv) << 16);
            o.y = (unsigned int)f2bf(s2 * dv) | ((unsigned int)f2bf(s3 * dv) << 16);
            ((uint2*)u2b)[(size_t)v2 * 4 + jq] = o;
        }
    }
}

// ---------------- fused pull2 + classifier (16B gather, 4 streams) -----------

__global__ __launch_bounds__(256) void k_pull2f(const int* __restrict__ row_ptr,
                                                const int* __restrict__ col_idx,
                                                const float* __restrict__ dinv,
                                                const unsigned int* __restrict__ u2b,
                                                const float* __restrict__ b2,
                                                const float* __restrict__ Wc,
                                                const float* __restrict__ bc,
                                                float* __restrict__ out) {
    __shared__ float hs[P_NODES][17];
    __shared__ float Wcs[H2 * NC];  // 128
    __shared__ float bcs[NC];
    __shared__ int lidx[P_CAP];     // 12 KB
    const int tid = threadIdx.x;
    if (tid < H2 * NC) Wcs[tid] = Wc[tid];
    if (tid < NC) bcs[tid] = bc[tid];
    const int v0 = blockIdx.x * P_NODES;
    const int base_off = row_ptr[v0];
    const int range = row_ptr[v0 + P_NODES] - base_off;
    const bool ovf = (range > P_CAP);
    const int stg = ovf ? 0 : range;
    for (int j = tid; j < stg; j += 256) lidx[j] = col_idx[base_off + j];
    __syncthreads();
    const int n = tid >> 3;         // node-in-block 0..31
    const int st = (tid >> 1) & 3;  // edge stream 0..3
    const int sub = tid & 1;        // feature half (16B = 8 bf16)
    const int v = v0 + n;
    const uint4* b16 = (const uint4*)u2b;
    float a[8];
#pragma unroll
    for (int k = 0; k < 8; ++k) a[k] = 0.0f;
    if (st == 0) acc8b(a, b16[(size_t)v * 2 + sub]);   // self-loop once
    const int beg = row_ptr[v] - base_off;
    const int end = row_ptr[v + 1] - base_off;
    int i = beg + st;
    if (!ovf) {
        for (; i + 12 < end; i += 16) {                // 4 edges/stream iter
            const int s0 = lidx[i];
            const int s1 = lidx[i + 4];
            const int s2 = lidx[i + 8];
            const int s3 = lidx[i + 12];
            const uint4 q0 = b16[(size_t)s0 * 2 + sub];
            const uint4 q1 = b16[(size_t)s1 * 2 + sub];
            const uint4 q2 = b16[(size_t)s2 * 2 + sub];
            const uint4 q3 = b16[(size_t)s3 * 2 + sub];
            acc8b(a, q0); acc8b(a, q1); acc8b(a, q2); acc8b(a, q3);
        }
        for (; i < end; i += 4) {
            acc8b(a, b16[(size_t)lidx[i] * 2 + sub]);
        }
    } else {
        const int* gp = col_idx + base_off;
        for (; i + 12 < end; i += 16) {
            const int s0 = gp[i];
            const int s1 = gp[i + 4];
            const int s2 = gp[i + 8];
            const int s3 = gp[i + 12];
            const uint4 q0 = b16[(size_t)s0 * 2 + sub];
            const uint4 q1 = b16[(size_t)s1 * 2 + sub];
            const uint4 q2 = b16[(size_t)s2 * 2 + sub];
            const uint4 q3 = b16[(size_t)s3 * 2 + sub];
            acc8b(a, q0); acc8b(a, q1); acc8b(a, q2); acc8b(a, q3);
        }
        for (; i < end; i += 4) {
            acc8b(a, b16[(size_t)gp[i] * 2 + sub]);
        }
    }
    // combine the 4 streams (xor over stream bits 1,2 of tid)
#pragma unroll
    for (int k = 0; k < 8; ++k) a[k] += __shfl_xor(a[k], 2, 64);
#pragma unroll
    for (int k = 0; k < 8; ++k) a[k] += __shfl_xor(a[k], 4, 64);
    if (st == 0) {
        const float dv = dinv[v];
        float bb[8];
        *(float4*)&bb[0] = ((const float4*)b2)[sub * 2 + 0];
        *(float4*)&bb[4] = ((const float4*)b2)[sub * 2 + 1];
        float* hp = &hs[n][sub * 8];
#pragma unroll
        for (int k = 0; k < 8; ++k)
            hp[k] = fmaxf(fmaf(a[k], dv, bb[k]), 0.0f);
    }
    __syncthreads();
    if (tid < P_NODES) {
        const int vv = v0 + tid;
        float lg[NC];
#pragma unroll
        for (int j = 0; j < NC; ++j) lg[j] = bcs[j];
#pragma unroll
        for (int k = 0; k < H2; ++k) {
            const float hk = hs[tid][k];
#pragma unroll
            for (int j = 0; j < NC; ++j)
                lg[j] = fmaf(hk, Wcs[k * NC + j], lg[j]);
        }
        float m = lg[0];
#pragma unroll
        for (int j = 1; j < NC; ++j) m = fmaxf(m, lg[j]);
        float s = 0.0f;
#pragma unroll
        for (int j = 0; j < NC; ++j) s += expf(lg[j] - m);
        const float lse = logf(s) + m;
        float4 o0, o1;
        o0.x = lg[0] - lse; o0.y = lg[1] - lse;
        o0.z = lg[2] - lse; o0.w = lg[3] - lse;
        o1.x = lg[4] - lse; o1.y = lg[5] - lse;
        o1.z = lg[6] - lse; o1.w = lg[7] - lse;
        float4* op = (float4*)(out + (size_t)vv * NC);
        op[0] = o0; op[1] = o1;
    }
}

// ---------------- host launch ----------------

extern "C" void kernel_launch(void* const* d_in, const int* in_sizes, int n_in,
                              void* d_out, int out_size, void* d_ws, size_t ws_size,
                              hipStream_t stream) {
    const float* x   = (const float*)d_in[0];
    const int*   ei  = (const int*)d_in[1];
    const float* W1  = (const float*)d_in[2];
    const float* b1  = (const float*)d_in[3];
    const float* W2  = (const float*)d_in[4];
    const float* b2  = (const float*)d_in[5];
    const float* Wc  = (const float*)d_in[6];
    const float* bc  = (const float*)d_in[7];
    float* out = (float*)d_out;

    // workspace layout (int units). ~41.2 MB total.
    int*   bucket_cursor = (int*)d_ws;                       // 1024 (NB2=782 used)
    float* dinv          = (float*)(bucket_cursor + 1024);   // 100000
    int*   degc          = (int*)dinv + 100000;              // 100096
    int*   bbase         = degc + 100096;                    // 1024 (783 used)
    int*   row_ptr       = bbase + 1024;                     // 100016 (100001 used)
    int*   col_idx       = row_ptr + 100016;                 // 3200000
    unsigned int* u1q    = (unsigned int*)(col_idx + 3200000); // 800000 dwords
    unsigned int* u2b    = u1q + 800000;                     // 800000 dwords
    int*   ebuf          = (int*)(u2b + 800000);             // NB2*BCAP2 = 4804608
    // y16 (bf16 x@W1, 6.4 MB) aliases col_idx (lifetimes disjoint).
    unsigned short* y16  = (unsigned short*)col_idx;         // 100096*32 shorts

    (void)hipMemsetAsync(bucket_cursor, 0, 1024 * sizeof(int), stream);
    k_pre <<<NSB + 391, 512, 0, stream>>>(ei, x, W1, bucket_cursor, ebuf, y16);
    k_mid <<<391, 512, 0, stream>>>(ebuf, bucket_cursor, y16, degc, dinv, bbase, u1q);
    k_fuse1<<<NB2, 512, 0, stream>>>(ebuf, bucket_cursor, degc, bbase, u1q, b1, W2, row_ptr, col_idx, u2b);
    k_pull2f<<<N_NODES / P_NODES, 256, 0, stream>>>(row_ptr, col_idx, dinv, u2b, b2, Wc, bc, out);
}